// Round 2
// baseline (10357.769 us; speedup 1.0000x reference)
//
#include <hip/hip_runtime.h>
#include <math.h>

#define HD 1024          // hidden size H
#define BB 64            // batch B
#define TT 256           // seq len T
#define GG (3 * HD)      // 3H = 3072

// ---------------- ws layout (bytes) ----------------
// W_comb : [3072][1024] f32   @ 0                (12,582,912)
// b_comb : [3072] f32         @ 12,582,912       (12,288)
// xg     : [T][G][B] f32      @ 12,595,200       (201,326,592)   layout (t, g, b)
// ht0    : [H][B] f32         @ 213,921,792      (262,144)       h transposed [k][b]
// ht1    : [H][B] f32         @ 214,183,936      (262,144)
// bar    : u32                @ 214,446,080
static constexpr size_t OFF_WCOMB = 0;
static constexpr size_t OFF_BCOMB = 12582912;
static constexpr size_t OFF_XG    = 12595200;
static constexpr size_t OFF_HT0   = 213921792;
static constexpr size_t OFF_HT1   = 214183936;
static constexpr size_t OFF_BAR   = 214446080;

__device__ __forceinline__ float sigmoidf_(float x) {
    return 1.0f / (1.0f + expf(-x));
}

// -------------------------------------------------------------------------
// init: transpose h0 (B,H) -> ht0 [k][b]; zero grid barrier counter
__global__ void k_init(const float* __restrict__ hidden, float* __restrict__ ht0,
                       unsigned* __restrict__ bar) {
    int idx = blockIdx.x * 256 + threadIdx.x;      // 65536 total
    int k = idx >> 6;
    int b = idx & 63;
    ht0[idx] = hidden[(size_t)b * HD + k];
    if (idx == 0) *bar = 0u;
}

// -------------------------------------------------------------------------
// fold: W_comb[g][d] = sum_h W_ih[g][h] * W_in[h][d]
// grid (48, 16), block 256; tile 64(m=g) x 64(n=d), kc=32, per-thread 4x4
__global__ __launch_bounds__(256) void k_fold(const float* __restrict__ A,   // W_ih 3072x1024
                                              const float* __restrict__ Bw,  // W_in 1024x1024
                                              float* __restrict__ C) {       // W_comb 3072x1024
    __shared__ __align__(16) float As[32][68];   // [k][m]
    __shared__ __align__(16) float Bs[32][68];   // [k][n]
    const int m0 = blockIdx.x * 64;
    const int n0 = blockIdx.y * 64;
    const int tid = threadIdx.x;
    const int r = (tid & 15) * 4;   // m offset
    const int c = (tid >> 4) * 4;   // n offset
    float acc[4][4] = {};
    for (int k0 = 0; k0 < HD; k0 += 32) {
        #pragma unroll
        for (int i = 0; i < 2; ++i) {
            int s = tid + i * 256;
            int row = s >> 3;          // m 0..63
            int c4 = (s & 7) * 4;      // k 0..28
            float4 v = *reinterpret_cast<const float4*>(&A[(size_t)(m0 + row) * HD + k0 + c4]);
            As[c4 + 0][row] = v.x; As[c4 + 1][row] = v.y;
            As[c4 + 2][row] = v.z; As[c4 + 3][row] = v.w;
        }
        #pragma unroll
        for (int i = 0; i < 2; ++i) {
            int s = tid + i * 256;
            int row = s >> 4;          // k 0..31
            int c4 = (s & 15) * 4;     // n 0..60
            float4 v = *reinterpret_cast<const float4*>(&Bw[(size_t)(k0 + row) * HD + n0 + c4]);
            *reinterpret_cast<float4*>(&Bs[row][c4]) = v;
        }
        __syncthreads();
        #pragma unroll
        for (int kk = 0; kk < 32; ++kk) {
            float4 av = *reinterpret_cast<const float4*>(&As[kk][r]);
            float4 bv = *reinterpret_cast<const float4*>(&Bs[kk][c]);
            float a_[4] = {av.x, av.y, av.z, av.w};
            float b_[4] = {bv.x, bv.y, bv.z, bv.w};
            #pragma unroll
            for (int i = 0; i < 4; ++i)
                #pragma unroll
                for (int j = 0; j < 4; ++j)
                    acc[i][j] += a_[i] * b_[j];
        }
        __syncthreads();
    }
    #pragma unroll
    for (int i = 0; i < 4; ++i) {
        float4 v = {acc[i][0], acc[i][1], acc[i][2], acc[i][3]};
        *reinterpret_cast<float4*>(&C[(size_t)(m0 + r + i) * HD + n0 + c]) = v;
    }
}

// -------------------------------------------------------------------------
// b_comb[g] = sum_h W_ih[g][h]*b_in[h] + b_ih[g]; one wave per g
__global__ void k_bcomb(const float* __restrict__ W_ih, const float* __restrict__ b_in,
                        const float* __restrict__ b_ih, float* __restrict__ b_comb) {
    int g = (blockIdx.x * blockDim.x + threadIdx.x) >> 6;   // 3072 waves
    int lane = threadIdx.x & 63;
    float s = 0.f;
    for (int k = lane; k < HD; k += 64) s += W_ih[(size_t)g * HD + k] * b_in[k];
    #pragma unroll
    for (int off = 32; off > 0; off >>= 1) s += __shfl_down(s, off);
    if (lane == 0) b_comb[g] = s + b_ih[g];
}

// -------------------------------------------------------------------------
// xg[t][g][b] = sum_d wi[b][t][d] * W_comb[g][d] + b_comb[g]
// grid (256 t, 12 g-tiles), block 256; tile 64(b) x 256(g), kc=32, 8x8/thread
__global__ __launch_bounds__(256) void k_xgates(const float* __restrict__ wi,
                                                const float* __restrict__ Wc,
                                                const float* __restrict__ bc,
                                                float* __restrict__ xg) {
    __shared__ __align__(16) float As[32][72];    // [k][b]  64 + pad
    __shared__ __align__(16) float Bs[32][264];   // [k][g]  256 + pad
    const int t = blockIdx.x;
    const int g0 = blockIdx.y * 256;
    const int tid = threadIdx.x;
    const int r = (tid & 7) * 8;    // b offset (8 wide)
    const int c = (tid >> 3) * 8;   // g offset (8 wide)
    float acc[8][8] = {};           // [b][g]
    for (int k0 = 0; k0 < HD; k0 += 32) {
        // stage A: 64 b x 32 k  (512 float4)
        #pragma unroll
        for (int i = 0; i < 2; ++i) {
            int s = tid + i * 256;
            int row = s >> 3;        // b 0..63
            int c4 = (s & 7) * 4;    // k
            float4 v = *reinterpret_cast<const float4*>(
                &wi[((size_t)row * TT + t) * HD + k0 + c4]);
            As[c4 + 0][row] = v.x; As[c4 + 1][row] = v.y;
            As[c4 + 2][row] = v.z; As[c4 + 3][row] = v.w;
        }
        // stage B: 256 g x 32 k  (2048 float4)
        #pragma unroll
        for (int i = 0; i < 8; ++i) {
            int s = tid + i * 256;
            int row = s >> 3;        // g 0..255
            int c4 = (s & 7) * 4;    // k
            float4 v = *reinterpret_cast<const float4*>(
                &Wc[(size_t)(g0 + row) * HD + k0 + c4]);
            Bs[c4 + 0][row] = v.x; Bs[c4 + 1][row] = v.y;
            Bs[c4 + 2][row] = v.z; Bs[c4 + 3][row] = v.w;
        }
        __syncthreads();
        #pragma unroll
        for (int kk = 0; kk < 32; ++kk) {
            float4 a0 = *reinterpret_cast<const float4*>(&As[kk][r]);
            float4 a1 = *reinterpret_cast<const float4*>(&As[kk][r + 4]);
            float4 b0 = *reinterpret_cast<const float4*>(&Bs[kk][c]);
            float4 b1 = *reinterpret_cast<const float4*>(&Bs[kk][c + 4]);
            float a_[8] = {a0.x, a0.y, a0.z, a0.w, a1.x, a1.y, a1.z, a1.w};
            float b_[8] = {b0.x, b0.y, b0.z, b0.w, b1.x, b1.y, b1.z, b1.w};
            #pragma unroll
            for (int i = 0; i < 8; ++i)
                #pragma unroll
                for (int j = 0; j < 8; ++j)
                    acc[i][j] += a_[i] * b_[j];
        }
        __syncthreads();
    }
    const size_t base = (size_t)t * GG * BB;
    #pragma unroll
    for (int j = 0; j < 8; ++j) {
        int g = g0 + c + j;
        float bias = bc[g];
        float4 v0 = {acc[0][j] + bias, acc[1][j] + bias, acc[2][j] + bias, acc[3][j] + bias};
        float4 v1 = {acc[4][j] + bias, acc[5][j] + bias, acc[6][j] + bias, acc[7][j] + bias};
        *reinterpret_cast<float4*>(&xg[base + (size_t)g * BB + r]) = v0;
        *reinterpret_cast<float4*>(&xg[base + (size_t)g * BB + r + 4]) = v1;
    }
}

// -------------------------------------------------------------------------
// persistent GRU scan v2: 256 blocks x 256 threads; block owns j0..j0+3 (12 gate rows).
// W rows LDS-resident across all steps (broadcast reads); wave = k-team (k-split 4),
// lane = b; 12 accs/thread; cross-team LDS reduction; agent-scope grid barrier.
#define SCAN_JPB 4
__global__ __launch_bounds__(256, 1) void k_scan(const float* __restrict__ Whh,
                                                 const float* __restrict__ bhh,
                                                 const float* __restrict__ xg,
                                                 float* __restrict__ ht0,
                                                 float* __restrict__ ht1,
                                                 unsigned* __restrict__ bar) {
    __shared__ __align__(16) float ws[12][HD];   // 48 KB: rows r = g*4+jj -> Whh[g*HD + j0+jj]
    __shared__ float red[4][12][BB];             // 12 KB partial sums
    const int tid = threadIdx.x;
    const int b = tid & 63;
    const int team = tid >> 6;                   // 0..3: k-team AND jj for finalize
    const int j0 = blockIdx.x * SCAN_JPB;
    const unsigned nblk = gridDim.x;

    // stage 12 W rows once (3072 float4)
    for (int idx = tid; idx < 12 * (HD / 4); idx += 256) {
        int rr = idx >> 8;                       // 0..11
        int k4 = idx & 255;
        int grow = (rr >> 2) * HD + j0 + (rr & 3);
        float4 v = *reinterpret_cast<const float4*>(&Whh[(size_t)grow * HD + k4 * 4]);
        *reinterpret_cast<float4*>(&ws[rr][k4 * 4]) = v;
    }
    __syncthreads();

    const int kbeg = team * 256;
    for (int t = 0; t < TT; ++t) {
        const float* hc = (t & 1) ? ht1 : ht0;
        float* hn = (t & 1) ? ht0 : ht1;
        float acc[12] = {};
        const float* hcb = hc + b;
        #pragma unroll 2
        for (int k = kbeg; k < kbeg + 256; k += 4) {
            float hv0 = hcb[(size_t)(k + 0) * 64];
            float hv1 = hcb[(size_t)(k + 1) * 64];
            float hv2 = hcb[(size_t)(k + 2) * 64];
            float hv3 = hcb[(size_t)(k + 3) * 64];
            #pragma unroll
            for (int rr = 0; rr < 12; ++rr) {
                float4 wv = *reinterpret_cast<const float4*>(&ws[rr][k]);
                acc[rr] += wv.x * hv0 + wv.y * hv1 + wv.z * hv2 + wv.w * hv3;
            }
        }
        #pragma unroll
        for (int rr = 0; rr < 12; ++rr) red[team][rr][b] = acc[rr];
        __syncthreads();
        // finalize: thread handles (b, jj = team)
        {
            const int jj = team;
            const int jg = j0 + jj;
            float s[3];
            #pragma unroll
            for (int g = 0; g < 3; ++g) {
                int rr = g * 4 + jj;
                s[g] = red[0][rr][b] + red[1][rr][b] + red[2][rr][b] + red[3][rr][b]
                     + bhh[(size_t)g * HD + jg];
            }
            const size_t tb = (size_t)t * GG * BB;
            float xr = xg[tb + (size_t)(0 * HD + jg) * BB + b];
            float xz = xg[tb + (size_t)(1 * HD + jg) * BB + b];
            float xn = xg[tb + (size_t)(2 * HD + jg) * BB + b];
            float rg = sigmoidf_(xr + s[0]);
            float zg = sigmoidf_(xz + s[1]);
            float ng = tanhf(xn + rg * s[2]);
            float hold = hc[(size_t)jg * 64 + b];
            hn[(size_t)jg * 64 + b] = (1.0f - zg) * ng + zg * hold;
        }
        __syncthreads();   // red reads + hn writes done (block-local)
        if (tid == 0) {
            __hip_atomic_fetch_add(bar, 1u, __ATOMIC_RELEASE, __HIP_MEMORY_SCOPE_AGENT);
            unsigned tgt = nblk * (unsigned)(t + 1);
            while (__hip_atomic_load(bar, __ATOMIC_ACQUIRE, __HIP_MEMORY_SCOPE_AGENT) < tgt) {
                __builtin_amdgcn_s_sleep(2);
            }
        }
        __syncthreads();
    }
}

// -------------------------------------------------------------------------
// out_last[b][o] = sum_k h_T[b][k] * W_out[o][k] + b_out[o]; h_T is ht0 [k][b]
__global__ __launch_bounds__(256) void k_out(const float* __restrict__ ht,
                                             const float* __restrict__ Wout,
                                             const float* __restrict__ bout,
                                             float* __restrict__ out) {
    __shared__ __align__(16) float hs[128][68];
    __shared__ __align__(16) float wsl[16][128];
    const int tid = threadIdx.x;
    const int o0 = blockIdx.x * 16;
    const int b = tid & 63;
    const int obase = tid >> 6;
    float acc[4] = {};
    for (int k0 = 0; k0 < HD; k0 += 128) {
        #pragma unroll
        for (int i = 0; i < 8; ++i) {
            int s = tid + i * 256;
            int k = s >> 4;
            int bb = (s & 15) * 4;
            float4 v = *reinterpret_cast<const float4*>(&ht[(size_t)k0 * 64 + (size_t)s * 4]);
            *reinterpret_cast<float4*>(&hs[k][bb]) = v;
        }
        for (int s = tid; s < 16 * 32; s += 256) {
            int rr = s >> 5;
            int c4 = (s & 31) * 4;
            float4 v = *reinterpret_cast<const float4*>(&Wout[(size_t)(o0 + rr) * HD + k0 + c4]);
            *reinterpret_cast<float4*>(&wsl[rr][c4]) = v;
        }
        __syncthreads();
        for (int kk = 0; kk < 128; kk += 4) {
            float hv[4];
            #pragma unroll
            for (int u = 0; u < 4; ++u) hv[u] = hs[kk + u][b];
            #pragma unroll
            for (int i = 0; i < 4; ++i) {
                float4 wv = *reinterpret_cast<const float4*>(&wsl[obase + 4 * i][kk]);
                acc[i] += hv[0] * wv.x + hv[1] * wv.y + hv[2] * wv.z + hv[3] * wv.w;
            }
        }
        __syncthreads();
    }
    #pragma unroll
    for (int i = 0; i < 4; ++i) {
        int o = o0 + obase + 4 * i;
        out[(size_t)b * 1024 + o] = acc[i] + bout[o];
    }
}

// hidden_out[b][h] = ht0[h][b], written at d_out + 65536
__global__ void k_hout(const float* __restrict__ ht, float* __restrict__ outp) {
    int idx = blockIdx.x * 256 + threadIdx.x;   // 65536
    int b = idx >> 10;
    int hh = idx & 1023;
    outp[idx] = ht[(size_t)hh * 64 + b];
}

// -------------------------------------------------------------------------
extern "C" void kernel_launch(void* const* d_in, const int* in_sizes, int n_in,
                              void* d_out, int out_size, void* d_ws, size_t ws_size,
                              hipStream_t stream) {
    (void)in_sizes; (void)n_in; (void)out_size; (void)ws_size;
    const float* wi     = (const float*)d_in[0];   // (B,T,1024)
    const float* hidden = (const float*)d_in[1];   // (1,B,H)
    const float* W_in   = (const float*)d_in[2];   // (H,1024)
    const float* b_in   = (const float*)d_in[3];
    const float* W_ih   = (const float*)d_in[4];   // (3H,H)
    const float* b_ih   = (const float*)d_in[5];
    const float* W_hh   = (const float*)d_in[6];   // (3H,H)
    const float* b_hh   = (const float*)d_in[7];
    const float* W_out  = (const float*)d_in[8];   // (1024,H)
    const float* b_out  = (const float*)d_in[9];

    char* ws = (char*)d_ws;
    float*    wcomb = (float*)(ws + OFF_WCOMB);
    float*    bcomb = (float*)(ws + OFF_BCOMB);
    float*    xg    = (float*)(ws + OFF_XG);
    float*    ht0   = (float*)(ws + OFF_HT0);
    float*    ht1   = (float*)(ws + OFF_HT1);
    unsigned* bar   = (unsigned*)(ws + OFF_BAR);
    float*    out   = (float*)d_out;

    k_init<<<256, 256, 0, stream>>>(hidden, ht0, bar);
    k_fold<<<dim3(48, 16), 256, 0, stream>>>(W_ih, W_in, wcomb);
    k_bcomb<<<768, 256, 0, stream>>>(W_ih, b_in, b_ih, bcomb);
    k_xgates<<<dim3(256, 12), 256, 0, stream>>>(wi, wcomb, bcomb, xg);
    k_scan<<<256, 256, 0, stream>>>(W_hh, b_hh, xg, ht0, ht1, bar);
    k_out<<<64, 256, 0, stream>>>(ht0, W_out, b_out, out);
    k_hout<<<256, 256, 0, stream>>>(ht0, out + 65536);
}

// Round 3
// 8073.424 us; speedup vs baseline: 1.2829x; 1.2829x over previous
//
#include <hip/hip_runtime.h>
#include <math.h>

#define HD 1024          // hidden size H
#define BB 64            // batch B
#define TT 256           // seq len T
#define GG (3 * HD)      // 3H = 3072

// ---------------- ws layout (bytes) ----------------
static constexpr size_t OFF_WCOMB = 0;
static constexpr size_t OFF_BCOMB = 12582912;
static constexpr size_t OFF_XG    = 12595200;
static constexpr size_t OFF_HT0   = 213921792;
static constexpr size_t OFF_HT1   = 214183936;
static constexpr size_t OFF_BAR   = 214446080;

__device__ __forceinline__ float sigmoidf_(float x) {
    return 1.0f / (1.0f + expf(-x));
}

// -------------------------------------------------------------------------
// init: transpose h0 (B,H) -> ht0 [k][b]; zero grid barrier counter
__global__ void k_init(const float* __restrict__ hidden, float* __restrict__ ht0,
                       unsigned* __restrict__ bar) {
    int idx = blockIdx.x * 256 + threadIdx.x;      // 65536 total
    int k = idx >> 6;
    int b = idx & 63;
    ht0[idx] = hidden[(size_t)b * HD + k];
    if (idx == 0) *bar = 0u;
}

// -------------------------------------------------------------------------
// fold: W_comb[g][d] = sum_h W_ih[g][h] * W_in[h][d]
__global__ __launch_bounds__(256) void k_fold(const float* __restrict__ A,   // W_ih 3072x1024
                                              const float* __restrict__ Bw,  // W_in 1024x1024
                                              float* __restrict__ C) {       // W_comb 3072x1024
    __shared__ __align__(16) float As[32][68];   // [k][m]
    __shared__ __align__(16) float Bs[32][68];   // [k][n]
    const int m0 = blockIdx.x * 64;
    const int n0 = blockIdx.y * 64;
    const int tid = threadIdx.x;
    const int r = (tid & 15) * 4;   // m offset
    const int c = (tid >> 4) * 4;   // n offset
    float acc[4][4] = {};
    for (int k0 = 0; k0 < HD; k0 += 32) {
        #pragma unroll
        for (int i = 0; i < 2; ++i) {
            int s = tid + i * 256;
            int row = s >> 3;          // m 0..63
            int c4 = (s & 7) * 4;      // k 0..28
            float4 v = *reinterpret_cast<const float4*>(&A[(size_t)(m0 + row) * HD + k0 + c4]);
            As[c4 + 0][row] = v.x; As[c4 + 1][row] = v.y;
            As[c4 + 2][row] = v.z; As[c4 + 3][row] = v.w;
        }
        #pragma unroll
        for (int i = 0; i < 2; ++i) {
            int s = tid + i * 256;
            int row = s >> 4;          // k 0..31
            int c4 = (s & 15) * 4;     // n 0..60
            float4 v = *reinterpret_cast<const float4*>(&Bw[(size_t)(k0 + row) * HD + n0 + c4]);
            *reinterpret_cast<float4*>(&Bs[row][c4]) = v;
        }
        __syncthreads();
        #pragma unroll
        for (int kk = 0; kk < 32; ++kk) {
            float4 av = *reinterpret_cast<const float4*>(&As[kk][r]);
            float4 bv = *reinterpret_cast<const float4*>(&Bs[kk][c]);
            float a_[4] = {av.x, av.y, av.z, av.w};
            float b_[4] = {bv.x, bv.y, bv.z, bv.w};
            #pragma unroll
            for (int i = 0; i < 4; ++i)
                #pragma unroll
                for (int j = 0; j < 4; ++j)
                    acc[i][j] += a_[i] * b_[j];
        }
        __syncthreads();
    }
    #pragma unroll
    for (int i = 0; i < 4; ++i) {
        float4 v = {acc[i][0], acc[i][1], acc[i][2], acc[i][3]};
        *reinterpret_cast<float4*>(&C[(size_t)(m0 + r + i) * HD + n0 + c]) = v;
    }
}

// -------------------------------------------------------------------------
__global__ void k_bcomb(const float* __restrict__ W_ih, const float* __restrict__ b_in,
                        const float* __restrict__ b_ih, float* __restrict__ b_comb) {
    int g = (blockIdx.x * blockDim.x + threadIdx.x) >> 6;   // 3072 waves
    int lane = threadIdx.x & 63;
    float s = 0.f;
    for (int k = lane; k < HD; k += 64) s += W_ih[(size_t)g * HD + k] * b_in[k];
    #pragma unroll
    for (int off = 32; off > 0; off >>= 1) s += __shfl_down(s, off);
    if (lane == 0) b_comb[g] = s + b_ih[g];
}

// -------------------------------------------------------------------------
// xg[t][g][b] = sum_d wi[b][t][d] * W_comb[g][d] + b_comb[g]
__global__ __launch_bounds__(256) void k_xgates(const float* __restrict__ wi,
                                                const float* __restrict__ Wc,
                                                const float* __restrict__ bc,
                                                float* __restrict__ xg) {
    __shared__ __align__(16) float As[32][72];    // [k][b]
    __shared__ __align__(16) float Bs[32][264];   // [k][g]
    const int t = blockIdx.x;
    const int g0 = blockIdx.y * 256;
    const int tid = threadIdx.x;
    const int r = (tid & 7) * 8;    // b offset
    const int c = (tid >> 3) * 8;   // g offset
    float acc[8][8] = {};           // [b][g]
    for (int k0 = 0; k0 < HD; k0 += 32) {
        #pragma unroll
        for (int i = 0; i < 2; ++i) {
            int s = tid + i * 256;
            int row = s >> 3;        // b 0..63
            int c4 = (s & 7) * 4;    // k
            float4 v = *reinterpret_cast<const float4*>(
                &wi[((size_t)row * TT + t) * HD + k0 + c4]);
            As[c4 + 0][row] = v.x; As[c4 + 1][row] = v.y;
            As[c4 + 2][row] = v.z; As[c4 + 3][row] = v.w;
        }
        #pragma unroll
        for (int i = 0; i < 8; ++i) {
            int s = tid + i * 256;
            int row = s >> 3;        // g 0..255
            int c4 = (s & 7) * 4;    // k
            float4 v = *reinterpret_cast<const float4*>(
                &Wc[(size_t)(g0 + row) * HD + k0 + c4]);
            Bs[c4 + 0][row] = v.x; Bs[c4 + 1][row] = v.y;
            Bs[c4 + 2][row] = v.z; Bs[c4 + 3][row] = v.w;
        }
        __syncthreads();
        #pragma unroll
        for (int kk = 0; kk < 32; ++kk) {
            float4 a0 = *reinterpret_cast<const float4*>(&As[kk][r]);
            float4 a1 = *reinterpret_cast<const float4*>(&As[kk][r + 4]);
            float4 b0 = *reinterpret_cast<const float4*>(&Bs[kk][c]);
            float4 b1 = *reinterpret_cast<const float4*>(&Bs[kk][c + 4]);
            float a_[8] = {a0.x, a0.y, a0.z, a0.w, a1.x, a1.y, a1.z, a1.w};
            float b_[8] = {b0.x, b0.y, b0.z, b0.w, b1.x, b1.y, b1.z, b1.w};
            #pragma unroll
            for (int i = 0; i < 8; ++i)
                #pragma unroll
                for (int j = 0; j < 8; ++j)
                    acc[i][j] += a_[i] * b_[j];
        }
        __syncthreads();
    }
    const size_t base = (size_t)t * GG * BB;
    #pragma unroll
    for (int j = 0; j < 8; ++j) {
        int g = g0 + c + j;
        float bias = bc[g];
        float4 v0 = {acc[0][j] + bias, acc[1][j] + bias, acc[2][j] + bias, acc[3][j] + bias};
        float4 v1 = {acc[4][j] + bias, acc[5][j] + bias, acc[6][j] + bias, acc[7][j] + bias};
        *reinterpret_cast<float4*>(&xg[base + (size_t)g * BB + r]) = v0;
        *reinterpret_cast<float4*>(&xg[base + (size_t)g * BB + r + 4]) = v1;
    }
}

// -------------------------------------------------------------------------
// persistent GRU scan v3: 256 blocks x 512 threads (8 waves, 2/SIMD).
// Block owns j0..j0+3 (12 gate rows). W rows LDS-resident (broadcast b128 reads).
// k-split 8: wave = k-team (128 k each), lane = b; 12 accs/thread; LDS reduce.
// h loads: coalesced b32 from global (L2-resident), 8 independent per burst.
#define SCAN_JPB 4
__global__ __launch_bounds__(512, 1) void k_scan(const float* __restrict__ Whh,
                                                 const float* __restrict__ bhh,
                                                 const float* __restrict__ xg,
                                                 float* __restrict__ ht0,
                                                 float* __restrict__ ht1,
                                                 unsigned* __restrict__ bar) {
    __shared__ __align__(16) float ws[12][HD];   // 48 KB
    __shared__ float red[8][12][BB];             // 24 KB
    const int tid = threadIdx.x;
    const int b = tid & 63;
    const int team = tid >> 6;                   // 0..7 k-team; teams 0..3 also finalize jj=team
    const int j0 = blockIdx.x * SCAN_JPB;
    const unsigned nblk = gridDim.x;

    // stage 12 W rows once (3072 float4)
    for (int idx = tid; idx < 12 * (HD / 4); idx += 512) {
        int rr = idx >> 8;                       // 0..11
        int k4 = idx & 255;
        int grow = (rr >> 2) * HD + j0 + (rr & 3);
        float4 v = *reinterpret_cast<const float4*>(&Whh[(size_t)grow * HD + k4 * 4]);
        *reinterpret_cast<float4*>(&ws[rr][k4 * 4]) = v;
    }
    __syncthreads();

    const int kbeg = team * 128;
    for (int t = 0; t < TT; ++t) {
        const float* hc = (t & 1) ? ht1 : ht0;
        float* hn = (t & 1) ? ht0 : ht1;

        // prefetch finalize operands (teams 0..3): xg triple + h_old
        float xr = 0.f, xz = 0.f, xn = 0.f, hold = 0.f;
        int jg = j0 + team;
        if (team < 4) {
            const size_t tb = (size_t)t * GG * BB;
            xr = xg[tb + (size_t)(0 * HD + jg) * BB + b];
            xz = xg[tb + (size_t)(1 * HD + jg) * BB + b];
            xn = xg[tb + (size_t)(2 * HD + jg) * BB + b];
            hold = hc[(size_t)jg * 64 + b];
        }

        float acc[12] = {};
        const float* hcb = hc + b + (size_t)kbeg * 64;
        #pragma unroll 2
        for (int kk = 0; kk < 128; kk += 8) {
            float hv[8];
            #pragma unroll
            for (int u = 0; u < 8; ++u) hv[u] = hcb[(size_t)(kk + u) * 64];
            #pragma unroll
            for (int rr = 0; rr < 12; ++rr) {
                const float* wr = &ws[rr][kbeg + kk];
                float4 w0 = *reinterpret_cast<const float4*>(wr);
                float4 w1 = *reinterpret_cast<const float4*>(wr + 4);
                acc[rr] += w0.x * hv[0] + w0.y * hv[1] + w0.z * hv[2] + w0.w * hv[3]
                         + w1.x * hv[4] + w1.y * hv[5] + w1.z * hv[6] + w1.w * hv[7];
            }
        }
        #pragma unroll
        for (int rr = 0; rr < 12; ++rr) red[team][rr][b] = acc[rr];
        __syncthreads();

        if (team < 4) {
            const int jj = team;
            float s[3];
            #pragma unroll
            for (int g = 0; g < 3; ++g) {
                int rr = g * 4 + jj;
                float sum = 0.f;
                #pragma unroll
                for (int tm = 0; tm < 8; ++tm) sum += red[tm][rr][b];
                s[g] = sum + bhh[(size_t)g * HD + jg];
            }
            float rg = sigmoidf_(xr + s[0]);
            float zg = sigmoidf_(xz + s[1]);
            float ng = tanhf(xn + rg * s[2]);
            hn[(size_t)jg * 64 + b] = (1.0f - zg) * ng + zg * hold;
        }
        __syncthreads();   // red reads + hn writes done (block-local)

        if (tid == 0) {
            __hip_atomic_fetch_add(bar, 1u, __ATOMIC_RELEASE, __HIP_MEMORY_SCOPE_AGENT);
            unsigned tgt = nblk * (unsigned)(t + 1);
            while (__hip_atomic_load(bar, __ATOMIC_ACQUIRE, __HIP_MEMORY_SCOPE_AGENT) < tgt) {
                __builtin_amdgcn_s_sleep(2);
            }
        }
        __syncthreads();
    }
}

// -------------------------------------------------------------------------
// out_last[b][o] = sum_k h_T[b][k] * W_out[o][k] + b_out[o]; h_T is ht0 [k][b]
__global__ __launch_bounds__(256) void k_out(const float* __restrict__ ht,
                                             const float* __restrict__ Wout,
                                             const float* __restrict__ bout,
                                             float* __restrict__ out) {
    __shared__ __align__(16) float hs[128][68];
    __shared__ __align__(16) float wsl[16][128];
    const int tid = threadIdx.x;
    const int o0 = blockIdx.x * 16;
    const int b = tid & 63;
    const int obase = tid >> 6;
    float acc[4] = {};
    for (int k0 = 0; k0 < HD; k0 += 128) {
        #pragma unroll
        for (int i = 0; i < 8; ++i) {
            int s = tid + i * 256;
            int k = s >> 4;
            int bb = (s & 15) * 4;
            float4 v = *reinterpret_cast<const float4*>(&ht[(size_t)k0 * 64 + (size_t)s * 4]);
            *reinterpret_cast<float4*>(&hs[k][bb]) = v;
        }
        for (int s = tid; s < 16 * 32; s += 256) {
            int rr = s >> 5;
            int c4 = (s & 31) * 4;
            float4 v = *reinterpret_cast<const float4*>(&Wout[(size_t)(o0 + rr) * HD + k0 + c4]);
            *reinterpret_cast<float4*>(&wsl[rr][c4]) = v;
        }
        __syncthreads();
        for (int kk = 0; kk < 128; kk += 4) {
            float hv[4];
            #pragma unroll
            for (int u = 0; u < 4; ++u) hv[u] = hs[kk + u][b];
            #pragma unroll
            for (int i = 0; i < 4; ++i) {
                float4 wv = *reinterpret_cast<const float4*>(&wsl[obase + 4 * i][kk]);
                acc[i] += hv[0] * wv.x + hv[1] * wv.y + hv[2] * wv.z + hv[3] * wv.w;
            }
        }
        __syncthreads();
    }
    #pragma unroll
    for (int i = 0; i < 4; ++i) {
        int o = o0 + obase + 4 * i;
        out[(size_t)b * 1024 + o] = acc[i] + bout[o];
    }
}

// hidden_out[b][h] = ht0[h][b], written at d_out + 65536
__global__ void k_hout(const float* __restrict__ ht, float* __restrict__ outp) {
    int idx = blockIdx.x * 256 + threadIdx.x;   // 65536
    int b = idx >> 10;
    int hh = idx & 1023;
    outp[idx] = ht[(size_t)hh * 64 + b];
}

// -------------------------------------------------------------------------
extern "C" void kernel_launch(void* const* d_in, const int* in_sizes, int n_in,
                              void* d_out, int out_size, void* d_ws, size_t ws_size,
                              hipStream_t stream) {
    (void)in_sizes; (void)n_in; (void)out_size; (void)ws_size;
    const float* wi     = (const float*)d_in[0];   // (B,T,1024)
    const float* hidden = (const float*)d_in[1];   // (1,B,H)
    const float* W_in   = (const float*)d_in[2];   // (H,1024)
    const float* b_in   = (const float*)d_in[3];
    const float* W_ih   = (const float*)d_in[4];   // (3H,H)
    const float* b_ih   = (const float*)d_in[5];
    const float* W_hh   = (const float*)d_in[6];   // (3H,H)
    const float* b_hh   = (const float*)d_in[7];
    const float* W_out  = (const float*)d_in[8];   // (1024,H)
    const float* b_out  = (const float*)d_in[9];

    char* ws = (char*)d_ws;
    float*    wcomb = (float*)(ws + OFF_WCOMB);
    float*    bcomb = (float*)(ws + OFF_BCOMB);
    float*    xg    = (float*)(ws + OFF_XG);
    float*    ht0   = (float*)(ws + OFF_HT0);
    float*    ht1   = (float*)(ws + OFF_HT1);
    unsigned* bar   = (unsigned*)(ws + OFF_BAR);
    float*    out   = (float*)d_out;

    k_init<<<256, 256, 0, stream>>>(hidden, ht0, bar);
    k_fold<<<dim3(48, 16), 256, 0, stream>>>(W_ih, W_in, wcomb);
    k_bcomb<<<768, 256, 0, stream>>>(W_ih, b_in, b_ih, bcomb);
    k_xgates<<<dim3(256, 12), 256, 0, stream>>>(wi, wcomb, bcomb, xg);
    k_scan<<<256, 512, 0, stream>>>(W_hh, b_hh, xg, ht0, ht1, bar);
    k_out<<<64, 256, 0, stream>>>(ht0, W_out, b_out, out);
    k_hout<<<256, 256, 0, stream>>>(ht0, out + 65536);
}

// Round 6
// 8015.938 us; speedup vs baseline: 1.2921x; 1.0072x over previous
//
#include <hip/hip_runtime.h>
#include <hip/hip_fp16.h>
#include <math.h>

#define HD 1024          // hidden size H
#define BB 64            // batch B
#define TT 256           // seq len T
#define GG (3 * HD)      // 3H = 3072

// ---------------- ws layout (bytes) ----------------
// W_comb : [3072][1024] f32 @ 0          (12,582,912)
// b_comb : [3072] f32       @ 12,582,912 (12,288)
// xg     : [T][G][B] f32    @ 12,595,200 (201,326,592)   layout (t, g, b)
// h16a   : paired fp16 h    @ 213,921,792 (131,072)      [k/2][b][2] ping
// h16b   : paired fp16 h    @ 214,052,864 (131,072)      pong
// hfin   : [H][B] f32       @ 214,183,936 (262,144)      final h (fp32)
// bar    : u32              @ 214,446,080
static constexpr size_t OFF_WCOMB = 0;
static constexpr size_t OFF_BCOMB = 12582912;
static constexpr size_t OFF_XG    = 12595200;
static constexpr size_t OFF_H16A  = 213921792;
static constexpr size_t OFF_H16B  = 214052864;
static constexpr size_t OFF_HFIN  = 214183936;
static constexpr size_t OFF_BAR   = 214446080;

// paired-h index: element (k,b) lives at (k>>1)*128 + (b<<1) + (k&1)
__device__ __forceinline__ int hp_idx(int k, int b) {
    return ((k >> 1) << 7) + (b << 1) + (k & 1);
}

__device__ __forceinline__ float sigmoidf_(float x) {
    return 1.0f / (1.0f + expf(-x));
}

// -------------------------------------------------------------------------
// init: h0 (B,H) -> h16a paired layout; zero grid barrier counter
__global__ void k_init(const float* __restrict__ hidden, __half* __restrict__ h16a,
                       unsigned* __restrict__ bar) {
    int idx = blockIdx.x * 256 + threadIdx.x;      // 65536 total
    int k = idx >> 6;
    int b = idx & 63;
    h16a[hp_idx(k, b)] = __float2half(hidden[(size_t)b * HD + k]);
    if (idx == 0) *bar = 0u;
}

// -------------------------------------------------------------------------
// fold: W_comb[g][d] = sum_h W_ih[g][h] * W_in[h][d]
__global__ __launch_bounds__(256) void k_fold(const float* __restrict__ A,   // W_ih 3072x1024
                                              const float* __restrict__ Bw,  // W_in 1024x1024
                                              float* __restrict__ C) {       // W_comb 3072x1024
    __shared__ __align__(16) float As[32][68];   // [k][m]
    __shared__ __align__(16) float Bs[32][68];   // [k][n]
    const int m0 = blockIdx.x * 64;
    const int n0 = blockIdx.y * 64;
    const int tid = threadIdx.x;
    const int r = (tid & 15) * 4;   // m offset
    const int c = (tid >> 4) * 4;   // n offset
    float acc[4][4] = {};
    for (int k0 = 0; k0 < HD; k0 += 32) {
        #pragma unroll
        for (int i = 0; i < 2; ++i) {
            int s = tid + i * 256;
            int row = s >> 3;          // m 0..63
            int c4 = (s & 7) * 4;      // k 0..28
            float4 v = *reinterpret_cast<const float4*>(&A[(size_t)(m0 + row) * HD + k0 + c4]);
            As[c4 + 0][row] = v.x; As[c4 + 1][row] = v.y;
            As[c4 + 2][row] = v.z; As[c4 + 3][row] = v.w;
        }
        #pragma unroll
        for (int i = 0; i < 2; ++i) {
            int s = tid + i * 256;
            int row = s >> 4;          // k 0..31
            int c4 = (s & 15) * 4;     // n 0..60
            float4 v = *reinterpret_cast<const float4*>(&Bw[(size_t)(k0 + row) * HD + n0 + c4]);
            *reinterpret_cast<float4*>(&Bs[row][c4]) = v;
        }
        __syncthreads();
        #pragma unroll
        for (int kk = 0; kk < 32; ++kk) {
            float4 av = *reinterpret_cast<const float4*>(&As[kk][r]);
            float4 bv = *reinterpret_cast<const float4*>(&Bs[kk][c]);
            float a_[4] = {av.x, av.y, av.z, av.w};
            float b_[4] = {bv.x, bv.y, bv.z, bv.w};
            #pragma unroll
            for (int i = 0; i < 4; ++i)
                #pragma unroll
                for (int j = 0; j < 4; ++j)
                    acc[i][j] += a_[i] * b_[j];
        }
        __syncthreads();
    }
    #pragma unroll
    for (int i = 0; i < 4; ++i) {
        float4 v = {acc[i][0], acc[i][1], acc[i][2], acc[i][3]};
        *reinterpret_cast<float4*>(&C[(size_t)(m0 + r + i) * HD + n0 + c]) = v;
    }
}

// -------------------------------------------------------------------------
__global__ void k_bcomb(const float* __restrict__ W_ih, const float* __restrict__ b_in,
                        const float* __restrict__ b_ih, float* __restrict__ b_comb) {
    int g = (blockIdx.x * blockDim.x + threadIdx.x) >> 6;   // 3072 waves
    int lane = threadIdx.x & 63;
    float s = 0.f;
    for (int k = lane; k < HD; k += 64) s += W_ih[(size_t)g * HD + k] * b_in[k];
    #pragma unroll
    for (int off = 32; off > 0; off >>= 1) s += __shfl_down(s, off);
    if (lane == 0) b_comb[g] = s + b_ih[g];
}

// -------------------------------------------------------------------------
// xg[t][g][b] = sum_d wi[b][t][d] * W_comb[g][d] + b_comb[g]
__global__ __launch_bounds__(256) void k_xgates(const float* __restrict__ wi,
                                                const float* __restrict__ Wc,
                                                const float* __restrict__ bc,
                                                float* __restrict__ xg) {
    __shared__ __align__(16) float As[32][72];    // [k][b]
    __shared__ __align__(16) float Bs[32][264];   // [k][g]
    const int t = blockIdx.x;
    const int g0 = blockIdx.y * 256;
    const int tid = threadIdx.x;
    const int r = (tid & 7) * 8;    // b offset
    const int c = (tid >> 3) * 8;   // g offset
    float acc[8][8] = {};           // [b][g]
    for (int k0 = 0; k0 < HD; k0 += 32) {
        #pragma unroll
        for (int i = 0; i < 2; ++i) {
            int s = tid + i * 256;
            int row = s >> 3;        // b 0..63
            int c4 = (s & 7) * 4;    // k
            float4 v = *reinterpret_cast<const float4*>(
                &wi[((size_t)row * TT + t) * HD + k0 + c4]);
            As[c4 + 0][row] = v.x; As[c4 + 1][row] = v.y;
            As[c4 + 2][row] = v.z; As[c4 + 3][row] = v.w;
        }
        #pragma unroll
        for (int i = 0; i < 8; ++i) {
            int s = tid + i * 256;
            int row = s >> 3;        // g 0..255
            int c4 = (s & 7) * 4;    // k
            float4 v = *reinterpret_cast<const float4*>(
                &Wc[(size_t)(g0 + row) * HD + k0 + c4]);
            Bs[c4 + 0][row] = v.x; Bs[c4 + 1][row] = v.y;
            Bs[c4 + 2][row] = v.z; Bs[c4 + 3][row] = v.w;
        }
        __syncthreads();
        #pragma unroll
        for (int kk = 0; kk < 32; ++kk) {
            float4 a0 = *reinterpret_cast<const float4*>(&As[kk][r]);
            float4 a1 = *reinterpret_cast<const float4*>(&As[kk][r + 4]);
            float4 b0 = *reinterpret_cast<const float4*>(&Bs[kk][c]);
            float4 b1 = *reinterpret_cast<const float4*>(&Bs[kk][c + 4]);
            float a_[8] = {a0.x, a0.y, a0.z, a0.w, a1.x, a1.y, a1.z, a1.w};
            float b_[8] = {b0.x, b0.y, b0.z, b0.w, b1.x, b1.y, b1.z, b1.w};
            #pragma unroll
            for (int i = 0; i < 8; ++i)
                #pragma unroll
                for (int j = 0; j < 8; ++j)
                    acc[i][j] += a_[i] * b_[j];
        }
        __syncthreads();
    }
    const size_t base = (size_t)t * GG * BB;
    #pragma unroll
    for (int j = 0; j < 8; ++j) {
        int g = g0 + c + j;
        float bias = bc[g];
        float4 v0 = {acc[0][j] + bias, acc[1][j] + bias, acc[2][j] + bias, acc[3][j] + bias};
        float4 v1 = {acc[4][j] + bias, acc[5][j] + bias, acc[6][j] + bias, acc[7][j] + bias};
        *reinterpret_cast<float4*>(&xg[base + (size_t)g * BB + r]) = v0;
        *reinterpret_cast<float4*>(&xg[base + (size_t)g * BB + r + 4]) = v1;
    }
}

// -------------------------------------------------------------------------
// persistent GRU scan v5: 256 blocks x 512 threads (8 waves).
// h state: paired fp16 [k/2][b][2] double buffer -> __half2 loads (256 B/instr);
// block-rotated k-range assignment de-phases the 256-block L3 broadcast sweep;
// h_old carried in fp32 registers; xg(t+1) prefetched BEFORE the grid barrier;
// W rows LDS-resident; k-split 8; LDS cross-team reduce.
#define SCAN_JPB 4
__global__ __launch_bounds__(512, 1) void k_scan(const float* __restrict__ Whh,
                                                 const float* __restrict__ bhh,
                                                 const float* __restrict__ xg,
                                                 const float* __restrict__ hidden,
                                                 __half* __restrict__ h16a,
                                                 __half* __restrict__ h16b,
                                                 float* __restrict__ hfin,
                                                 unsigned* __restrict__ bar) {
    __shared__ __align__(16) float ws[12][HD];   // 48 KB
    __shared__ float red[8][12][BB];             // 24 KB
    const int tid = threadIdx.x;
    const int b = tid & 63;
    const int team = tid >> 6;                   // 0..7 k-team; teams 0..3 finalize jj=team
    const int j0 = blockIdx.x * SCAN_JPB;
    const unsigned nblk = gridDim.x;

    // stage 12 W rows once (3072 float4)
    for (int idx = tid; idx < 12 * (HD / 4); idx += 512) {
        int rr = idx >> 8;                       // 0..11
        int k4 = idx & 255;
        int grow = (rr >> 2) * HD + j0 + (rr & 3);
        float4 v = *reinterpret_cast<const float4*>(&Whh[(size_t)grow * HD + k4 * 4]);
        *reinterpret_cast<float4*>(&ws[rr][k4 * 4]) = v;
    }

    // finalize-thread loop-invariants + t=0 operand prefetch
    const int jg = j0 + team;                    // valid for team<4
    float br = 0.f, bz = 0.f, bn = 0.f;
    float hold = 0.f, xr = 0.f, xz = 0.f, xn = 0.f;
    if (team < 4) {
        br = bhh[jg];
        bz = bhh[HD + jg];
        bn = bhh[2 * HD + jg];
        hold = hidden[(size_t)b * HD + jg];
        xr = xg[(size_t)(0 * HD + jg) * BB + b];
        xz = xg[(size_t)(1 * HD + jg) * BB + b];
        xn = xg[(size_t)(2 * HD + jg) * BB + b];
    }
    __syncthreads();

    // block-rotated k-range: bijective team->range map per block
    const int kbeg = ((team + blockIdx.x) & 7) * 128;
    for (int t = 0; t < TT; ++t) {
        const __half* hc = (t & 1) ? h16b : h16a;
        __half* hn = (t & 1) ? h16a : h16b;

        float acc[12] = {};
        const __half2* h2 = reinterpret_cast<const __half2*>(hc) + b;  // pair idx * 64 + b
        #pragma unroll 4
        for (int kk = 0; kk < 128; kk += 8) {
            const int pb = (kbeg + kk) >> 1;     // pair index base (kbeg,kk even)
            float hv[8];
            #pragma unroll
            for (int u = 0; u < 4; ++u) {
                float2 p = __half22float2(h2[(size_t)(pb + u) * 64]);
                hv[2 * u] = p.x; hv[2 * u + 1] = p.y;
            }
            #pragma unroll
            for (int rr = 0; rr < 12; ++rr) {
                const float* wr = &ws[rr][kbeg + kk];
                float4 w0 = *reinterpret_cast<const float4*>(wr);
                float4 w1 = *reinterpret_cast<const float4*>(wr + 4);
                acc[rr] += w0.x * hv[0] + w0.y * hv[1] + w0.z * hv[2] + w0.w * hv[3]
                         + w1.x * hv[4] + w1.y * hv[5] + w1.z * hv[6] + w1.w * hv[7];
            }
        }
        #pragma unroll
        for (int rr = 0; rr < 12; ++rr) red[team][rr][b] = acc[rr];
        __syncthreads();

        if (team < 4) {
            const int jj = team;
            float s0 = br, s1 = bz, s2 = bn;
            #pragma unroll
            for (int tm = 0; tm < 8; ++tm) s0 += red[tm][0 * 4 + jj][b];
            #pragma unroll
            for (int tm = 0; tm < 8; ++tm) s1 += red[tm][1 * 4 + jj][b];
            #pragma unroll
            for (int tm = 0; tm < 8; ++tm) s2 += red[tm][2 * 4 + jj][b];
            float rg = sigmoidf_(xr + s0);
            float zg = sigmoidf_(xz + s1);
            float ng = tanhf(xn + rg * s2);
            float hnew = (1.0f - zg) * ng + zg * hold;
            hn[hp_idx(jg, b)] = __float2half(hnew);
            if (t == TT - 1) hfin[(size_t)jg * 64 + b] = hnew;
            hold = hnew;
            // prefetch next step's xg BEFORE the barrier (latency hidden)
            if (t + 1 < TT) {
                const size_t tb = (size_t)(t + 1) * GG * BB;
                xr = xg[tb + (size_t)(0 * HD + jg) * BB + b];
                xz = xg[tb + (size_t)(1 * HD + jg) * BB + b];
                xn = xg[tb + (size_t)(2 * HD + jg) * BB + b];
            }
        }
        __syncthreads();   // red consumed + hn writes drained

        if (tid == 0) {
            __hip_atomic_fetch_add(bar, 1u, __ATOMIC_RELEASE, __HIP_MEMORY_SCOPE_AGENT);
            unsigned tgt = nblk * (unsigned)(t + 1);
            while (__hip_atomic_load(bar, __ATOMIC_RELAXED, __HIP_MEMORY_SCOPE_AGENT) < tgt) {
                __builtin_amdgcn_s_sleep(1);
            }
            (void)__hip_atomic_load(bar, __ATOMIC_ACQUIRE, __HIP_MEMORY_SCOPE_AGENT);
        }
        __syncthreads();
    }
}

// -------------------------------------------------------------------------
// out_last[b][o] = sum_k hfin[k][b] * W_out[o][k] + b_out[o]
__global__ __launch_bounds__(256) void k_out(const float* __restrict__ ht,
                                             const float* __restrict__ Wout,
                                             const float* __restrict__ bout,
                                             float* __restrict__ out) {
    __shared__ __align__(16) float hs[128][68];
    __shared__ __align__(16) float wsl[16][128];
    const int tid = threadIdx.x;
    const int o0 = blockIdx.x * 16;
    const int b = tid & 63;
    const int obase = tid >> 6;
    float acc[4] = {};
    for (int k0 = 0; k0 < HD; k0 += 128) {
        #pragma unroll
        for (int i = 0; i < 8; ++i) {
            int s = tid + i * 256;
            int k = s >> 4;
            int bb = (s & 15) * 4;
            float4 v = *reinterpret_cast<const float4*>(&ht[(size_t)k0 * 64 + (size_t)s * 4]);
            *reinterpret_cast<float4*>(&hs[k][bb]) = v;
        }
        for (int s = tid; s < 16 * 32; s += 256) {
            int rr = s >> 5;
            int c4 = (s & 31) * 4;
            float4 v = *reinterpret_cast<const float4*>(&Wout[(size_t)(o0 + rr) * HD + k0 + c4]);
            *reinterpret_cast<float4*>(&wsl[rr][c4]) = v;
        }
        __syncthreads();
        for (int kk = 0; kk < 128; kk += 4) {
            float hv[4];
            #pragma unroll
            for (int u = 0; u < 4; ++u) hv[u] = hs[kk + u][b];
            #pragma unroll
            for (int i = 0; i < 4; ++i) {
                float4 wv = *reinterpret_cast<const float4*>(&wsl[obase + 4 * i][kk]);
                acc[i] += hv[0] * wv.x + hv[1] * wv.y + hv[2] * wv.z + hv[3] * wv.w;
            }
        }
        __syncthreads();
    }
    #pragma unroll
    for (int i = 0; i < 4; ++i) {
        int o = o0 + obase + 4 * i;
        out[(size_t)b * 1024 + o] = acc[i] + bout[o];
    }
}

// hidden_out[b][h] = hfin[h][b], written at d_out + 65536
__global__ void k_hout(const float* __restrict__ ht, float* __restrict__ outp) {
    int idx = blockIdx.x * 256 + threadIdx.x;   // 65536
    int b = idx >> 10;
    int hh = idx & 1023;
    outp[idx] = ht[(size_t)hh * 64 + b];
}

// -------------------------------------------------------------------------
extern "C" void kernel_launch(void* const* d_in, const int* in_sizes, int n_in,
                              void* d_out, int out_size, void* d_ws, size_t ws_size,
                              hipStream_t stream) {
    (void)in_sizes; (void)n_in; (void)out_size; (void)ws_size;
    const float* wi     = (const float*)d_in[0];   // (B,T,1024)
    const float* hidden = (const float*)d_in[1];   // (1,B,H)
    const float* W_in   = (const float*)d_in[2];   // (H,1024)
    const float* b_in   = (const float*)d_in[3];
    const float* W_ih   = (const float*)d_in[4];   // (3H,H)
    const float* b_ih   = (const float*)d_in[5];
    const float* W_hh   = (const float*)d_in[6];   // (3H,H)
    const float* b_hh   = (const float*)d_in[7];
    const float* W_out  = (const float*)d_in[8];   // (1024,H)
    const float* b_out  = (const float*)d_in[9];

    char* ws = (char*)d_ws;
    float*    wcomb = (float*)(ws + OFF_WCOMB);
    float*    bcomb = (float*)(ws + OFF_BCOMB);
    float*    xg    = (float*)(ws + OFF_XG);
    __half*   h16a  = (__half*)(ws + OFF_H16A);
    __half*   h16b  = (__half*)(ws + OFF_H16B);
    float*    hfin  = (float*)(ws + OFF_HFIN);
    unsigned* bar   = (unsigned*)(ws + OFF_BAR);
    float*    out   = (float*)d_out;

    k_init<<<256, 256, 0, stream>>>(hidden, h16a, bar);
    k_fold<<<dim3(48, 16), 256, 0, stream>>>(W_ih, W_in, wcomb);
    k_bcomb<<<768, 256, 0, stream>>>(W_ih, b_in, b_ih, bcomb);
    k_xgates<<<dim3(256, 12), 256, 0, stream>>>(wi, wcomb, bcomb, xg);
    k_scan<<<256, 512, 0, stream>>>(W_hh, b_hh, xg, hidden, h16a, h16b, hfin, bar);
    k_out<<<64, 256, 0, stream>>>(hfin, W_out, b_out, out);
    k_hout<<<256, 256, 0, stream>>>(hfin, out + 65536);
}

// Round 7
// 6891.418 us; speedup vs baseline: 1.5030x; 1.1632x over previous
//
#include <hip/hip_runtime.h>
#include <hip/hip_fp16.h>
#include <math.h>

#define HD 1024          // hidden size H
#define BB 64            // batch B
#define TT 256           // seq len T
#define GG (3 * HD)      // 3H = 3072

// ---------------- ws layout (bytes) ----------------
// W_comb : [3072][1024] f32 @ 0          (12,582,912)
// b_comb : [3072] f32       @ 12,582,912 (12,288)
// xg     : [T][G][B] f32    @ 12,595,200 (201,326,592)   layout (t, g, b)
// h16a   : paired fp16 h    @ 213,921,792 (131,072)      [k/2][b][2] ping
// h16b   : paired fp16 h    @ 214,052,864 (131,072)      pong
// hfin   : [H][B] f32       @ 214,183,936 (262,144)      final h (fp32)
// bar    : 33 x 128B lines  @ 214,446,080 (4,224)        tree barrier
//          line 0 = root; lines 1..16 = grp[g]; lines 17..32 = rel[g]
static constexpr size_t OFF_WCOMB = 0;
static constexpr size_t OFF_BCOMB = 12582912;
static constexpr size_t OFF_XG    = 12595200;
static constexpr size_t OFF_H16A  = 213921792;
static constexpr size_t OFF_H16B  = 214052864;
static constexpr size_t OFF_HFIN  = 214183936;
static constexpr size_t OFF_BAR   = 214446080;

// paired-h index: element (k,b) lives at (k>>1)*128 + (b<<1) + (k&1)
__device__ __forceinline__ int hp_idx(int k, int b) {
    return ((k >> 1) << 7) + (b << 1) + (k & 1);
}

__device__ __forceinline__ float sigmoidf_(float x) {
    return 1.0f / (1.0f + expf(-x));
}

// -------------------------------------------------------------------------
// init: h0 (B,H) -> h16a paired layout; zero all tree-barrier lines
__global__ void k_init(const float* __restrict__ hidden, __half* __restrict__ h16a,
                       unsigned* __restrict__ bar) {
    int idx = blockIdx.x * 256 + threadIdx.x;      // 65536 total
    int k = idx >> 6;
    int b = idx & 63;
    h16a[hp_idx(k, b)] = __float2half(hidden[(size_t)b * HD + k]);
    if (idx < 33) bar[idx * 32] = 0u;              // one u32 per 128B line
}

// -------------------------------------------------------------------------
// fold: W_comb[g][d] = sum_h W_ih[g][h] * W_in[h][d]
__global__ __launch_bounds__(256) void k_fold(const float* __restrict__ A,   // W_ih 3072x1024
                                              const float* __restrict__ Bw,  // W_in 1024x1024
                                              float* __restrict__ C) {       // W_comb 3072x1024
    __shared__ __align__(16) float As[32][68];   // [k][m]
    __shared__ __align__(16) float Bs[32][68];   // [k][n]
    const int m0 = blockIdx.x * 64;
    const int n0 = blockIdx.y * 64;
    const int tid = threadIdx.x;
    const int r = (tid & 15) * 4;   // m offset
    const int c = (tid >> 4) * 4;   // n offset
    float acc[4][4] = {};
    for (int k0 = 0; k0 < HD; k0 += 32) {
        #pragma unroll
        for (int i = 0; i < 2; ++i) {
            int s = tid + i * 256;
            int row = s >> 3;          // m 0..63
            int c4 = (s & 7) * 4;      // k 0..28
            float4 v = *reinterpret_cast<const float4*>(&A[(size_t)(m0 + row) * HD + k0 + c4]);
            As[c4 + 0][row] = v.x; As[c4 + 1][row] = v.y;
            As[c4 + 2][row] = v.z; As[c4 + 3][row] = v.w;
        }
        #pragma unroll
        for (int i = 0; i < 2; ++i) {
            int s = tid + i * 256;
            int row = s >> 4;          // k 0..31
            int c4 = (s & 15) * 4;     // n 0..60
            float4 v = *reinterpret_cast<const float4*>(&Bw[(size_t)(k0 + row) * HD + n0 + c4]);
            *reinterpret_cast<float4*>(&Bs[row][c4]) = v;
        }
        __syncthreads();
        #pragma unroll
        for (int kk = 0; kk < 32; ++kk) {
            float4 av = *reinterpret_cast<const float4*>(&As[kk][r]);
            float4 bv = *reinterpret_cast<const float4*>(&Bs[kk][c]);
            float a_[4] = {av.x, av.y, av.z, av.w};
            float b_[4] = {bv.x, bv.y, bv.z, bv.w};
            #pragma unroll
            for (int i = 0; i < 4; ++i)
                #pragma unroll
                for (int j = 0; j < 4; ++j)
                    acc[i][j] += a_[i] * b_[j];
        }
        __syncthreads();
    }
    #pragma unroll
    for (int i = 0; i < 4; ++i) {
        float4 v = {acc[i][0], acc[i][1], acc[i][2], acc[i][3]};
        *reinterpret_cast<float4*>(&C[(size_t)(m0 + r + i) * HD + n0 + c]) = v;
    }
}

// -------------------------------------------------------------------------
__global__ void k_bcomb(const float* __restrict__ W_ih, const float* __restrict__ b_in,
                        const float* __restrict__ b_ih, float* __restrict__ b_comb) {
    int g = (blockIdx.x * blockDim.x + threadIdx.x) >> 6;   // 3072 waves
    int lane = threadIdx.x & 63;
    float s = 0.f;
    for (int k = lane; k < HD; k += 64) s += W_ih[(size_t)g * HD + k] * b_in[k];
    #pragma unroll
    for (int off = 32; off > 0; off >>= 1) s += __shfl_down(s, off);
    if (lane == 0) b_comb[g] = s + b_ih[g];
}

// -------------------------------------------------------------------------
// xg[t][g][b] = sum_d wi[b][t][d] * W_comb[g][d] + b_comb[g]
__global__ __launch_bounds__(256) void k_xgates(const float* __restrict__ wi,
                                                const float* __restrict__ Wc,
                                                const float* __restrict__ bc,
                                                float* __restrict__ xg) {
    __shared__ __align__(16) float As[32][72];    // [k][b]
    __shared__ __align__(16) float Bs[32][264];   // [k][g]
    const int t = blockIdx.x;
    const int g0 = blockIdx.y * 256;
    const int tid = threadIdx.x;
    const int r = (tid & 7) * 8;    // b offset
    const int c = (tid >> 3) * 8;   // g offset
    float acc[8][8] = {};           // [b][g]
    for (int k0 = 0; k0 < HD; k0 += 32) {
        #pragma unroll
        for (int i = 0; i < 2; ++i) {
            int s = tid + i * 256;
            int row = s >> 3;        // b 0..63
            int c4 = (s & 7) * 4;    // k
            float4 v = *reinterpret_cast<const float4*>(
                &wi[((size_t)row * TT + t) * HD + k0 + c4]);
            As[c4 + 0][row] = v.x; As[c4 + 1][row] = v.y;
            As[c4 + 2][row] = v.z; As[c4 + 3][row] = v.w;
        }
        #pragma unroll
        for (int i = 0; i < 8; ++i) {
            int s = tid + i * 256;
            int row = s >> 3;        // g 0..255
            int c4 = (s & 7) * 4;    // k
            float4 v = *reinterpret_cast<const float4*>(
                &Wc[(size_t)(g0 + row) * HD + k0 + c4]);
            Bs[c4 + 0][row] = v.x; Bs[c4 + 1][row] = v.y;
            Bs[c4 + 2][row] = v.z; Bs[c4 + 3][row] = v.w;
        }
        __syncthreads();
        #pragma unroll
        for (int kk = 0; kk < 32; ++kk) {
            float4 a0 = *reinterpret_cast<const float4*>(&As[kk][r]);
            float4 a1 = *reinterpret_cast<const float4*>(&As[kk][r + 4]);
            float4 b0 = *reinterpret_cast<const float4*>(&Bs[kk][c]);
            float4 b1 = *reinterpret_cast<const float4*>(&Bs[kk][c + 4]);
            float a_[8] = {a0.x, a0.y, a0.z, a0.w, a1.x, a1.y, a1.z, a1.w};
            float b_[8] = {b0.x, b0.y, b0.z, b0.w, b1.x, b1.y, b1.z, b1.w};
            #pragma unroll
            for (int i = 0; i < 8; ++i)
                #pragma unroll
                for (int j = 0; j < 8; ++j)
                    acc[i][j] += a_[i] * b_[j];
        }
        __syncthreads();
    }
    const size_t base = (size_t)t * GG * BB;
    #pragma unroll
    for (int j = 0; j < 8; ++j) {
        int g = g0 + c + j;
        float bias = bc[g];
        float4 v0 = {acc[0][j] + bias, acc[1][j] + bias, acc[2][j] + bias, acc[3][j] + bias};
        float4 v1 = {acc[4][j] + bias, acc[5][j] + bias, acc[6][j] + bias, acc[7][j] + bias};
        *reinterpret_cast<float4*>(&xg[base + (size_t)g * BB + r]) = v0;
        *reinterpret_cast<float4*>(&xg[base + (size_t)g * BB + r + 4]) = v1;
    }
}

// -------------------------------------------------------------------------
// persistent GRU scan v6: identical data path to v5; grid barrier replaced by a
// 2-level tree (16 groups x 16 blocks, monotonic counters, 128B-isolated lines).
// Serialized same-line RMWs drop 256 -> 16 per level. Release chain:
// member ACQ_REL RMW grp -> closer ACQ_REL RMW root -> closer ACQUIRE root,
// RELEASE store rel[g] -> member ACQUIRE rel[g].
#define SCAN_JPB 4
__global__ __launch_bounds__(512, 1) void k_scan(const float* __restrict__ Whh,
                                                 const float* __restrict__ bhh,
                                                 const float* __restrict__ xg,
                                                 const float* __restrict__ hidden,
                                                 __half* __restrict__ h16a,
                                                 __half* __restrict__ h16b,
                                                 float* __restrict__ hfin,
                                                 unsigned* __restrict__ bar) {
    __shared__ __align__(16) float ws[12][HD];   // 48 KB
    __shared__ float red[8][12][BB];             // 24 KB
    const int tid = threadIdx.x;
    const int b = tid & 63;
    const int team = tid >> 6;                   // 0..7 k-team; teams 0..3 finalize jj=team
    const int j0 = blockIdx.x * SCAN_JPB;

    // stage 12 W rows once (3072 float4)
    for (int idx = tid; idx < 12 * (HD / 4); idx += 512) {
        int rr = idx >> 8;                       // 0..11
        int k4 = idx & 255;
        int grow = (rr >> 2) * HD + j0 + (rr & 3);
        float4 v = *reinterpret_cast<const float4*>(&Whh[(size_t)grow * HD + k4 * 4]);
        *reinterpret_cast<float4*>(&ws[rr][k4 * 4]) = v;
    }

    // finalize-thread loop-invariants + t=0 operand prefetch
    const int jg = j0 + team;                    // valid for team<4
    float br = 0.f, bz = 0.f, bn = 0.f;
    float hold = 0.f, xr = 0.f, xz = 0.f, xn = 0.f;
    if (team < 4) {
        br = bhh[jg];
        bz = bhh[HD + jg];
        bn = bhh[2 * HD + jg];
        hold = hidden[(size_t)b * HD + jg];
        xr = xg[(size_t)(0 * HD + jg) * BB + b];
        xz = xg[(size_t)(1 * HD + jg) * BB + b];
        xn = xg[(size_t)(2 * HD + jg) * BB + b];
    }
    __syncthreads();

    // tree-barrier pointers (per-block constants)
    const int grpid = blockIdx.x >> 4;           // 16 groups of 16 blocks
    unsigned* const rootp = bar;                 // line 0
    unsigned* const grpp  = bar + 32 * (1 + grpid);
    unsigned* const relp  = bar + 32 * (17 + grpid);

    // block-rotated k-range: bijective team->range map per block
    const int kbeg = ((team + blockIdx.x) & 7) * 128;
    for (int t = 0; t < TT; ++t) {
        const __half* hc = (t & 1) ? h16b : h16a;
        __half* hn = (t & 1) ? h16a : h16b;

        float acc[12] = {};
        const __half2* h2 = reinterpret_cast<const __half2*>(hc) + b;  // pair idx * 64 + b
        #pragma unroll 4
        for (int kk = 0; kk < 128; kk += 8) {
            const int pb = (kbeg + kk) >> 1;     // pair index base (kbeg,kk even)
            float hv[8];
            #pragma unroll
            for (int u = 0; u < 4; ++u) {
                float2 p = __half22float2(h2[(size_t)(pb + u) * 64]);
                hv[2 * u] = p.x; hv[2 * u + 1] = p.y;
            }
            #pragma unroll
            for (int rr = 0; rr < 12; ++rr) {
                const float* wr = &ws[rr][kbeg + kk];
                float4 w0 = *reinterpret_cast<const float4*>(wr);
                float4 w1 = *reinterpret_cast<const float4*>(wr + 4);
                acc[rr] += w0.x * hv[0] + w0.y * hv[1] + w0.z * hv[2] + w0.w * hv[3]
                         + w1.x * hv[4] + w1.y * hv[5] + w1.z * hv[6] + w1.w * hv[7];
            }
        }
        #pragma unroll
        for (int rr = 0; rr < 12; ++rr) red[team][rr][b] = acc[rr];
        __syncthreads();

        if (team < 4) {
            const int jj = team;
            float s0 = br, s1 = bz, s2 = bn;
            #pragma unroll
            for (int tm = 0; tm < 8; ++tm) s0 += red[tm][0 * 4 + jj][b];
            #pragma unroll
            for (int tm = 0; tm < 8; ++tm) s1 += red[tm][1 * 4 + jj][b];
            #pragma unroll
            for (int tm = 0; tm < 8; ++tm) s2 += red[tm][2 * 4 + jj][b];
            float rg = sigmoidf_(xr + s0);
            float zg = sigmoidf_(xz + s1);
            float ng = tanhf(xn + rg * s2);
            float hnew = (1.0f - zg) * ng + zg * hold;
            hn[hp_idx(jg, b)] = __float2half(hnew);
            if (t == TT - 1) hfin[(size_t)jg * 64 + b] = hnew;
            hold = hnew;
            // prefetch next step's xg BEFORE the barrier (latency hidden)
            if (t + 1 < TT) {
                const size_t tb = (size_t)(t + 1) * GG * BB;
                xr = xg[tb + (size_t)(0 * HD + jg) * BB + b];
                xz = xg[tb + (size_t)(1 * HD + jg) * BB + b];
                xn = xg[tb + (size_t)(2 * HD + jg) * BB + b];
            }
        }
        __syncthreads();   // red consumed + hn writes drained (vmcnt0 at barrier)

        if (tid == 0) {
            const unsigned e = (unsigned)(t + 1);
            unsigned old = __hip_atomic_fetch_add(grpp, 1u, __ATOMIC_ACQ_REL,
                                                  __HIP_MEMORY_SCOPE_AGENT);
            if (old == 16u * e - 1u) {
                // group closer: arrive at root, wait for all 16 groups, publish
                __hip_atomic_fetch_add(rootp, 1u, __ATOMIC_ACQ_REL,
                                       __HIP_MEMORY_SCOPE_AGENT);
                while (__hip_atomic_load(rootp, __ATOMIC_RELAXED,
                                         __HIP_MEMORY_SCOPE_AGENT) < 16u * e) {
                    __builtin_amdgcn_s_sleep(1);
                }
                (void)__hip_atomic_load(rootp, __ATOMIC_ACQUIRE, __HIP_MEMORY_SCOPE_AGENT);
                __hip_atomic_store(relp, e, __ATOMIC_RELEASE, __HIP_MEMORY_SCOPE_AGENT);
            } else {
                while (__hip_atomic_load(relp, __ATOMIC_RELAXED,
                                         __HIP_MEMORY_SCOPE_AGENT) < e) {
                    __builtin_amdgcn_s_sleep(1);
                }
            }
            (void)__hip_atomic_load(relp, __ATOMIC_ACQUIRE, __HIP_MEMORY_SCOPE_AGENT);
        }
        __syncthreads();
    }
}

// -------------------------------------------------------------------------
// out_last[b][o] = sum_k hfin[k][b] * W_out[o][k] + b_out[o]
__global__ __launch_bounds__(256) void k_out(const float* __restrict__ ht,
                                             const float* __restrict__ Wout,
                                             const float* __restrict__ bout,
                                             float* __restrict__ out) {
    __shared__ __align__(16) float hs[128][68];
    __shared__ __align__(16) float wsl[16][128];
    const int tid = threadIdx.x;
    const int o0 = blockIdx.x * 16;
    const int b = tid & 63;
    const int obase = tid >> 6;
    float acc[4] = {};
    for (int k0 = 0; k0 < HD; k0 += 128) {
        #pragma unroll
        for (int i = 0; i < 8; ++i) {
            int s = tid + i * 256;
            int k = s >> 4;
            int bb = (s & 15) * 4;
            float4 v = *reinterpret_cast<const float4*>(&ht[(size_t)k0 * 64 + (size_t)s * 4]);
            *reinterpret_cast<float4*>(&hs[k][bb]) = v;
        }
        for (int s = tid; s < 16 * 32; s += 256) {
            int rr = s >> 5;
            int c4 = (s & 31) * 4;
            float4 v = *reinterpret_cast<const float4*>(&Wout[(size_t)(o0 + rr) * HD + k0 + c4]);
            *reinterpret_cast<float4*>(&wsl[rr][c4]) = v;
        }
        __syncthreads();
        for (int kk = 0; kk < 128; kk += 4) {
            float hv[4];
            #pragma unroll
            for (int u = 0; u < 4; ++u) hv[u] = hs[kk + u][b];
            #pragma unroll
            for (int i = 0; i < 4; ++i) {
                float4 wv = *reinterpret_cast<const float4*>(&wsl[obase + 4 * i][kk]);
                acc[i] += hv[0] * wv.x + hv[1] * wv.y + hv[2] * wv.z + hv[3] * wv.w;
            }
        }
        __syncthreads();
    }
    #pragma unroll
    for (int i = 0; i < 4; ++i) {
        int o = o0 + obase + 4 * i;
        out[(size_t)b * 1024 + o] = acc[i] + bout[o];
    }
}

// hidden_out[b][h] = hfin[h][b], written at d_out + 65536
__global__ void k_hout(const float* __restrict__ ht, float* __restrict__ outp) {
    int idx = blockIdx.x * 256 + threadIdx.x;   // 65536
    int b = idx >> 10;
    int hh = idx & 1023;
    outp[idx] = ht[(size_t)hh * 64 + b];
}

// -------------------------------------------------------------------------
extern "C" void kernel_launch(void* const* d_in, const int* in_sizes, int n_in,
                              void* d_out, int out_size, void* d_ws, size_t ws_size,
                              hipStream_t stream) {
    (void)in_sizes; (void)n_in; (void)out_size; (void)ws_size;
    const float* wi     = (const float*)d_in[0];   // (B,T,1024)
    const float* hidden = (const float*)d_in[1];   // (1,B,H)
    const float* W_in   = (const float*)d_in[2];   // (H,1024)
    const float* b_in   = (const float*)d_in[3];
    const float* W_ih   = (const float*)d_in[4];   // (3H,H)
    const float* b_ih   = (const float*)d_in[5];
    const float* W_hh   = (const float*)d_in[6];   // (3H,H)
    const float* b_hh   = (const float*)d_in[7];
    const float* W_out  = (const float*)d_in[8];   // (1024,H)
    const float* b_out  = (const float*)d_in[9];

    char* ws = (char*)d_ws;
    float*    wcomb = (float*)(ws + OFF_WCOMB);
    float*    bcomb = (float*)(ws + OFF_BCOMB);
    float*    xg    = (float*)(ws + OFF_XG);
    __half*   h16a  = (__half*)(ws + OFF_H16A);
    __half*   h16b  = (__half*)(ws + OFF_H16B);
    float*    hfin  = (float*)(ws + OFF_HFIN);
    unsigned* bar   = (unsigned*)(ws + OFF_BAR);
    float*    out   = (float*)d_out;

    k_init<<<256, 256, 0, stream>>>(hidden, h16a, bar);
    k_fold<<<dim3(48, 16), 256, 0, stream>>>(W_ih, W_in, wcomb);
    k_bcomb<<<768, 256, 0, stream>>>(W_ih, b_in, b_ih, bcomb);
    k_xgates<<<dim3(256, 12), 256, 0, stream>>>(wi, wcomb, bcomb, xg);
    k_scan<<<256, 512, 0, stream>>>(W_hh, b_hh, xg, hidden, h16a, h16b, hfin, bar);
    k_out<<<64, 256, 0, stream>>>(hfin, W_out, b_out, out);
    k_hout<<<256, 256, 0, stream>>>(hfin, out + 65536);
}

// Round 8
// 3860.662 us; speedup vs baseline: 2.6829x; 1.7850x over previous
//
#include <hip/hip_runtime.h>
#include <hip/hip_fp16.h>
#include <math.h>

#define HD 1024          // hidden size H
#define BB 64            // batch B
#define TT 256           // seq len T
#define GG (3 * HD)      // 3H = 3072
#define NSCAN 64         // scan blocks (JPB=16)
#define NPROD 192        // xg producer blocks

typedef _Float16 f16x8 __attribute__((ext_vector_type(8)));
typedef float f32x4 __attribute__((ext_vector_type(4)));

// ---------------- ws layout (bytes) ----------------
// W_comb : [3072][1024] f32 @ 0           (12,582,912)
// b_comb : [3072] f32       @ 12,582,912  (12,288)
// xg     : [T][G][B] f32    @ 12,595,200  (201,326,592)  layout (t, g, b)
// hta    : fp16 [b][k]      @ 213,921,792 (131,072)      h state ping
// htb    : fp16 [b][k]      @ 214,052,864 (131,072)      pong
// hfin   : [k][b] f32       @ 214,183,936 (262,144)      final h
// bar    : @ 214,446,080: line0=root, lines1-8=grp, 9-16=rel (128B each);
//          cnt[256] u32 at +2176 (xg per-t ready counters, target 12)
static constexpr size_t OFF_WCOMB = 0;
static constexpr size_t OFF_BCOMB = 12582912;
static constexpr size_t OFF_XG    = 12595200;
static constexpr size_t OFF_HTA   = 213921792;
static constexpr size_t OFF_HTB   = 214052864;
static constexpr size_t OFF_HFIN  = 214183936;
static constexpr size_t OFF_BAR   = 214446080;

__device__ __forceinline__ float sigmoidf_(float x) {
    return 1.0f / (1.0f + expf(-x));
}

// -------------------------------------------------------------------------
// init: h0 (B,H) -> hta fp16 [b][k] (same layout as hidden); zero barrier+cnt
__global__ void k_init(const float* __restrict__ hidden, __half* __restrict__ hta,
                       unsigned* __restrict__ bar) {
    int idx = blockIdx.x * 256 + threadIdx.x;      // 65536 total
    hta[idx] = __float2half(hidden[idx]);
    if (idx < 17) bar[idx * 32] = 0u;
    if (idx < 256) bar[544 + idx] = 0u;
}

// -------------------------------------------------------------------------
// fold: W_comb[g][d] = sum_h W_ih[g][h] * W_in[h][d]
__global__ __launch_bounds__(256) void k_fold(const float* __restrict__ A,
                                              const float* __restrict__ Bw,
                                              float* __restrict__ C) {
    __shared__ __align__(16) float As[32][68];
    __shared__ __align__(16) float Bs[32][68];
    const int m0 = blockIdx.x * 64;
    const int n0 = blockIdx.y * 64;
    const int tid = threadIdx.x;
    const int r = (tid & 15) * 4;
    const int c = (tid >> 4) * 4;
    float acc[4][4] = {};
    for (int k0 = 0; k0 < HD; k0 += 32) {
        #pragma unroll
        for (int i = 0; i < 2; ++i) {
            int s = tid + i * 256;
            int row = s >> 3;
            int c4 = (s & 7) * 4;
            float4 v = *reinterpret_cast<const float4*>(&A[(size_t)(m0 + row) * HD + k0 + c4]);
            As[c4 + 0][row] = v.x; As[c4 + 1][row] = v.y;
            As[c4 + 2][row] = v.z; As[c4 + 3][row] = v.w;
        }
        #pragma unroll
        for (int i = 0; i < 2; ++i) {
            int s = tid + i * 256;
            int row = s >> 4;
            int c4 = (s & 15) * 4;
            float4 v = *reinterpret_cast<const float4*>(&Bw[(size_t)(k0 + row) * HD + n0 + c4]);
            *reinterpret_cast<float4*>(&Bs[row][c4]) = v;
        }
        __syncthreads();
        #pragma unroll
        for (int kk = 0; kk < 32; ++kk) {
            float4 av = *reinterpret_cast<const float4*>(&As[kk][r]);
            float4 bv = *reinterpret_cast<const float4*>(&Bs[kk][c]);
            float a_[4] = {av.x, av.y, av.z, av.w};
            float b_[4] = {bv.x, bv.y, bv.z, bv.w};
            #pragma unroll
            for (int i = 0; i < 4; ++i)
                #pragma unroll
                for (int j = 0; j < 4; ++j)
                    acc[i][j] += a_[i] * b_[j];
        }
        __syncthreads();
    }
    #pragma unroll
    for (int i = 0; i < 4; ++i) {
        float4 v = {acc[i][0], acc[i][1], acc[i][2], acc[i][3]};
        *reinterpret_cast<float4*>(&C[(size_t)(m0 + r + i) * HD + n0 + c]) = v;
    }
}

// -------------------------------------------------------------------------
__global__ void k_bcomb(const float* __restrict__ W_ih, const float* __restrict__ b_in,
                        const float* __restrict__ b_ih, float* __restrict__ b_comb) {
    int g = (blockIdx.x * blockDim.x + threadIdx.x) >> 6;
    int lane = threadIdx.x & 63;
    float s = 0.f;
    for (int k = lane; k < HD; k += 64) s += W_ih[(size_t)g * HD + k] * b_in[k];
    #pragma unroll
    for (int off = 32; off > 0; off >>= 1) s += __shfl_down(s, off);
    if (lane == 0) b_comb[g] = s + b_ih[g];
}

// -------------------------------------------------------------------------
// fused: blocks 0..63 = persistent MFMA GRU scan; blocks 64..255 = xg producers.
// Scan block: owns j0..j0+15 (48 W rows = 3 gates x 16 j). A-frags (W fp16)
// register-resident for all 256 steps. Per step: stage h (fp16 [b][k]) into
// swizzled LDS, 6 working waves do 2 MFMA tiles each (12 = 3 gate-tiles x 4
// b-tiles), C via LDS, gate math on 512 threads, write h_new; 8x8 tree barrier
// + producer gate on cnt[t+1].
__global__ __launch_bounds__(512, 2) void k_fused(
        const float* __restrict__ Whh, const float* __restrict__ bhh,
        const float* __restrict__ wi,  const float* __restrict__ Wc,
        const float* __restrict__ bc,  float* __restrict__ xg,
        const float* __restrict__ hidden,
        __half* __restrict__ hta, __half* __restrict__ htb,
        float* __restrict__ hfin, unsigned* __restrict__ bar) {
    __shared__ __align__(16) char lds[131072];
    const int tid = threadIdx.x;
    unsigned* const cnt = bar + 544;

    if (blockIdx.x < NSCAN) {
        // ---------------- scan role ----------------
        char* const lh = lds;                         // fp16 [64][1024] swizzled
        float* const cred = reinterpret_cast<float*>(lds);  // overlay [48][68]
        const int bid = blockIdx.x;
        const int j0 = bid * 16;
        const int w  = tid >> 6;                      // wave 0..7
        const int l  = tid & 63;
        const int lg = l >> 4;                        // lane group 0..3
        const int ll = l & 15;
        const bool active = (w != 3 && w != 7);       // 6 working waves
        const int mt  = w & 3;                        // gate tile 0..2 (active)
        const int ntA = (w < 4) ? 0 : 1;
        const int ntB = ntA + 2;
        // finalize mapping: thread -> (b=fb, jj=fj) and (b=fb+32, jj=fj)
        const int fb = tid >> 4;                      // 0..31
        const int fj = tid & 15;
        const int jg = j0 + fj;

        // A fragments: 32 kb x 8 halves, k-contiguous fill (layout-permutation safe)
        f16x8 areg[32];
        if (active) {
            const float* wrow = Whh + (size_t)(mt * HD + j0 + ll) * HD;
            #pragma unroll
            for (int kb = 0; kb < 32; ++kb) {
                int k0 = kb * 32 + lg * 8;
                float4 u0 = *reinterpret_cast<const float4*>(wrow + k0);
                float4 u1 = *reinterpret_cast<const float4*>(wrow + k0 + 4);
                f16x8 a;
                a[0] = (_Float16)u0.x; a[1] = (_Float16)u0.y;
                a[2] = (_Float16)u0.z; a[3] = (_Float16)u0.w;
                a[4] = (_Float16)u1.x; a[5] = (_Float16)u1.y;
                a[6] = (_Float16)u1.z; a[7] = (_Float16)u1.w;
                areg[kb] = a;
            }
        }
        // finalize invariants
        const float br = bhh[jg], bz = bhh[HD + jg], bn = bhh[2 * HD + jg];
        float hold0 = hidden[(size_t)fb * HD + jg];
        float hold1 = hidden[(size_t)(fb + 32) * HD + jg];
        // barrier pointers (8 groups x 8 blocks)
        const int grp = bid >> 3;
        unsigned* const rootp = bar;
        unsigned* const grpp  = bar + 32 * (1 + grp);
        unsigned* const relp  = bar + 32 * (9 + grp);
        // B-frag lane rows
        const int bA = ntA * 16 + ll, sA = bA & 7;
        const int bB = ntB * 16 + ll, sB = bB & 7;

        // gate for xg[0]
        if (tid == 0) {
            while (__hip_atomic_load(&cnt[0], __ATOMIC_RELAXED, __HIP_MEMORY_SCOPE_AGENT) < 12u)
                __builtin_amdgcn_s_sleep(2);
            (void)__hip_atomic_load(&cnt[0], __ATOMIC_ACQUIRE, __HIP_MEMORY_SCOPE_AGENT);
        }
        __syncthreads();

        for (int t = 0; t < TT; ++t) {
            const __half* hc = (t & 1) ? htb : hta;
            __half* hnx = (t & 1) ? hta : htb;
            // prefetch xg[t] (ready per gate at end of previous step)
            const size_t tb = (size_t)t * GG * BB;
            float xr0 = xg[tb + (size_t)jg * BB + fb];
            float xz0 = xg[tb + (size_t)(HD + jg) * BB + fb];
            float xn0 = xg[tb + (size_t)(2 * HD + jg) * BB + fb];
            float xr1 = xg[tb + (size_t)jg * BB + fb + 32];
            float xz1 = xg[tb + (size_t)(HD + jg) * BB + fb + 32];
            float xn1 = xg[tb + (size_t)(2 * HD + jg) * BB + fb + 32];
            // stage h -> LDS, 16B chunks, XOR-swizzled (chunk ^= row&7)
            #pragma unroll
            for (int i = 0; i < 16; ++i) {
                int c = tid + i * 512;
                int row = c >> 7, kc = c & 127;
                float4 v = *reinterpret_cast<const float4*>(
                    reinterpret_cast<const char*>(hc) + (size_t)row * 2048 + kc * 16);
                *reinterpret_cast<float4*>(lh + row * 2048 + ((kc ^ (row & 7)) << 4)) = v;
            }
            __syncthreads();
            f32x4 acc0 = {0.f, 0.f, 0.f, 0.f}, acc1 = {0.f, 0.f, 0.f, 0.f};
            if (active) {
                #pragma unroll
                for (int kb = 0; kb < 32; ++kb) {
                    int kc = kb * 4 + lg;
                    f16x8 b0 = *reinterpret_cast<const f16x8*>(lh + bA * 2048 + ((kc ^ sA) << 4));
                    f16x8 b1 = *reinterpret_cast<const f16x8*>(lh + bB * 2048 + ((kc ^ sB) << 4));
                    acc0 = __builtin_amdgcn_mfma_f32_16x16x32_f16(areg[kb], b0, acc0, 0, 0, 0);
                    acc1 = __builtin_amdgcn_mfma_f32_16x16x32_f16(areg[kb], b1, acc1, 0, 0, 0);
                }
            }
            __syncthreads();   // all LDS h reads done before cred overlay
            if (active) {
                int rb = mt * 16 + lg * 4;
                #pragma unroll
                for (int i = 0; i < 4; ++i) {
                    cred[(rb + i) * 68 + ntA * 16 + ll] = acc0[i];
                    cred[(rb + i) * 68 + ntB * 16 + ll] = acc1[i];
                }
            }
            __syncthreads();
            // finalize 2 (j,b) pairs per thread
            {
                float s0 = cred[fj * 68 + fb] + br;
                float s1 = cred[(16 + fj) * 68 + fb] + bz;
                float s2 = cred[(32 + fj) * 68 + fb] + bn;
                float rg = sigmoidf_(xr0 + s0);
                float zg = sigmoidf_(xz0 + s1);
                float ng = tanhf(xn0 + rg * s2);
                float hn0 = (1.0f - zg) * ng + zg * hold0;
                hold0 = hn0;
                hnx[(size_t)fb * HD + jg] = __float2half(hn0);
                float u0 = cred[fj * 68 + fb + 32] + br;
                float u1 = cred[(16 + fj) * 68 + fb + 32] + bz;
                float u2 = cred[(32 + fj) * 68 + fb + 32] + bn;
                float rg1 = sigmoidf_(xr1 + u0);
                float zg1 = sigmoidf_(xz1 + u1);
                float ng1 = tanhf(xn1 + rg1 * u2);
                float hn1 = (1.0f - zg1) * ng1 + zg1 * hold1;
                hold1 = hn1;
                hnx[(size_t)(fb + 32) * HD + jg] = __float2half(hn1);
                if (t == TT - 1) {
                    hfin[(size_t)jg * 64 + fb] = hn0;
                    hfin[(size_t)jg * 64 + fb + 32] = hn1;
                }
            }
            __syncthreads();   // cred reads + h stores drained (vmcnt0 at barrier)
            // tree barrier + producer gate for xg[t+1]
            if (tid == 0) {
                const unsigned e = (unsigned)(t + 1);
                unsigned old = __hip_atomic_fetch_add(grpp, 1u, __ATOMIC_ACQ_REL,
                                                      __HIP_MEMORY_SCOPE_AGENT);
                if (old == 8u * e - 1u) {
                    __hip_atomic_fetch_add(rootp, 1u, __ATOMIC_ACQ_REL,
                                           __HIP_MEMORY_SCOPE_AGENT);
                    while (__hip_atomic_load(rootp, __ATOMIC_RELAXED,
                                             __HIP_MEMORY_SCOPE_AGENT) < 8u * e)
                        __builtin_amdgcn_s_sleep(1);
                    (void)__hip_atomic_load(rootp, __ATOMIC_ACQUIRE, __HIP_MEMORY_SCOPE_AGENT);
                    __hip_atomic_store(relp, e, __ATOMIC_RELEASE, __HIP_MEMORY_SCOPE_AGENT);
                } else {
                    while (__hip_atomic_load(relp, __ATOMIC_RELAXED,
                                             __HIP_MEMORY_SCOPE_AGENT) < e)
                        __builtin_amdgcn_s_sleep(1);
                }
                (void)__hip_atomic_load(relp, __ATOMIC_ACQUIRE, __HIP_MEMORY_SCOPE_AGENT);
                if (t + 1 < TT) {
                    while (__hip_atomic_load(&cnt[t + 1], __ATOMIC_RELAXED,
                                             __HIP_MEMORY_SCOPE_AGENT) < 12u)
                        __builtin_amdgcn_s_sleep(1);
                    (void)__hip_atomic_load(&cnt[t + 1], __ATOMIC_ACQUIRE,
                                            __HIP_MEMORY_SCOPE_AGENT);
                }
            }
            __syncthreads();
        }
    } else {
        // ---------------- xg producer role ----------------
        float* const As = reinterpret_cast<float*>(lds);          // [32][72]
        float* const Bs = reinterpret_cast<float*>(lds + 9216);   // [32][264]
        const int wid = blockIdx.x - NSCAN;                       // 0..191
        const int r = (tid & 7) * 8;     // b offset
        const int c = (tid >> 3) * 4;    // g offset
        for (int item = wid; item < TT * 12; item += NPROD) {
            const int t  = item / 12;
            const int g0 = (item % 12) * 256;
            float acc[8][4] = {};
            for (int k0 = 0; k0 < HD; k0 += 32) {
                {
                    int s = tid;                     // 512 chunks exactly
                    int row = s >> 3, c4 = (s & 7) * 4;
                    float4 v = *reinterpret_cast<const float4*>(
                        &wi[((size_t)row * TT + t) * HD + k0 + c4]);
                    As[(c4 + 0) * 72 + row] = v.x; As[(c4 + 1) * 72 + row] = v.y;
                    As[(c4 + 2) * 72 + row] = v.z; As[(c4 + 3) * 72 + row] = v.w;
                }
                #pragma unroll
                for (int i = 0; i < 4; ++i) {
                    int s = tid + i * 512;
                    int row = s >> 3, c4 = (s & 7) * 4;
                    float4 v = *reinterpret_cast<const float4*>(
                        &Wc[(size_t)(g0 + row) * HD + k0 + c4]);
                    Bs[(c4 + 0) * 264 + row] = v.x; Bs[(c4 + 1) * 264 + row] = v.y;
                    Bs[(c4 + 2) * 264 + row] = v.z; Bs[(c4 + 3) * 264 + row] = v.w;
                }
                __syncthreads();
                #pragma unroll
                for (int kk = 0; kk < 32; ++kk) {
                    float4 a0 = *reinterpret_cast<const float4*>(&As[kk * 72 + r]);
                    float4 a1 = *reinterpret_cast<const float4*>(&As[kk * 72 + r + 4]);
                    float4 bv = *reinterpret_cast<const float4*>(&Bs[kk * 264 + c]);
                    float a_[8] = {a0.x, a0.y, a0.z, a0.w, a1.x, a1.y, a1.z, a1.w};
                    float b_[4] = {bv.x, bv.y, bv.z, bv.w};
                    #pragma unroll
                    for (int i = 0; i < 8; ++i)
                        #pragma unroll
                        for (int j = 0; j < 4; ++j)
                            acc[i][j] += a_[i] * b_[j];
                }
                __syncthreads();
            }
            const size_t base = (size_t)t * GG * BB;
            #pragma unroll
            for (int j = 0; j < 4; ++j) {
                int g = g0 + c + j;
                float bias = bc[g];
                float4 v0 = {acc[0][j] + bias, acc[1][j] + bias,
                             acc[2][j] + bias, acc[3][j] + bias};
                float4 v1 = {acc[4][j] + bias, acc[5][j] + bias,
                             acc[6][j] + bias, acc[7][j] + bias};
                *reinterpret_cast<float4*>(&xg[base + (size_t)g * BB + r]) = v0;
                *reinterpret_cast<float4*>(&xg[base + (size_t)g * BB + r + 4]) = v1;
            }
            __syncthreads();   // all tile stores drained before publish
            if (tid == 0)
                __hip_atomic_fetch_add(&cnt[t], 1u, __ATOMIC_RELEASE,
                                       __HIP_MEMORY_SCOPE_AGENT);
        }
    }
}

// -------------------------------------------------------------------------
// out_last[b][o] = sum_k hfin[k][b] * W_out[o][k] + b_out[o]
__global__ __launch_bounds__(256) void k_out(const float* __restrict__ ht,
                                             const float* __restrict__ Wout,
                                             const float* __restrict__ bout,
                                             float* __restrict__ out) {
    __shared__ __align__(16) float hs[128][68];
    __shared__ __align__(16) float wsl[16][128];
    const int tid = threadIdx.x;
    const int o0 = blockIdx.x * 16;
    const int b = tid & 63;
    const int obase = tid >> 6;
    float acc[4] = {};
    for (int k0 = 0; k0 < HD; k0 += 128) {
        #pragma unroll
        for (int i = 0; i < 8; ++i) {
            int s = tid + i * 256;
            int k = s >> 4;
            int bb = (s & 15) * 4;
            float4 v = *reinterpret_cast<const float4*>(&ht[(size_t)k0 * 64 + (size_t)s * 4]);
            *reinterpret_cast<float4*>(&hs[k][bb]) = v;
        }
        for (int s = tid; s < 16 * 32; s += 256) {
            int rr = s >> 5;
            int c4 = (s & 31) * 4;
            float4 v = *reinterpret_cast<const float4*>(&Wout[(size_t)(o0 + rr) * HD + k0 + c4]);
            *reinterpret_cast<float4*>(&wsl[rr][c4]) = v;
        }
        __syncthreads();
        for (int kk = 0; kk < 128; kk += 4) {
            float hv[4];
            #pragma unroll
            for (int u = 0; u < 4; ++u) hv[u] = hs[kk + u][b];
            #pragma unroll
            for (int i = 0; i < 4; ++i) {
                float4 wv = *reinterpret_cast<const float4*>(&wsl[obase + 4 * i][kk]);
                acc[i] += hv[0] * wv.x + hv[1] * wv.y + hv[2] * wv.z + hv[3] * wv.w;
            }
        }
        __syncthreads();
    }
    #pragma unroll
    for (int i = 0; i < 4; ++i) {
        int o = o0 + obase + 4 * i;
        out[(size_t)b * 1024 + o] = acc[i] + bout[o];
    }
}

// hidden_out[b][h] = hfin[h][b], written at d_out + 65536
__global__ void k_hout(const float* __restrict__ ht, float* __restrict__ outp) {
    int idx = blockIdx.x * 256 + threadIdx.x;   // 65536
    int b = idx >> 10;
    int hh = idx & 1023;
    outp[idx] = ht[(size_t)hh * 64 + b];
}

// -------------------------------------------------------------------------
extern "C" void kernel_launch(void* const* d_in, const int* in_sizes, int n_in,
                              void* d_out, int out_size, void* d_ws, size_t ws_size,
                              hipStream_t stream) {
    (void)in_sizes; (void)n_in; (void)out_size; (void)ws_size;
    const float* wi     = (const float*)d_in[0];   // (B,T,1024)
    const float* hidden = (const float*)d_in[1];   // (1,B,H)
    const float* W_in   = (const float*)d_in[2];   // (H,1024)
    const float* b_in   = (const float*)d_in[3];
    const float* W_ih   = (const float*)d_in[4];   // (3H,H)
    const float* b_ih   = (const float*)d_in[5];
    const float* W_hh   = (const float*)d_in[6];   // (3H,H)
    const float* b_hh   = (const float*)d_in[7];
    const float* W_out  = (const float*)d_in[8];   // (1024,H)
    const float* b_out  = (const float*)d_in[9];

    char* ws = (char*)d_ws;
    float*    wcomb = (float*)(ws + OFF_WCOMB);
    float*    bcomb = (float*)(ws + OFF_BCOMB);
    float*    xg    = (float*)(ws + OFF_XG);
    __half*   hta   = (__half*)(ws + OFF_HTA);
    __half*   htb   = (__half*)(ws + OFF_HTB);
    float*    hfin  = (float*)(ws + OFF_HFIN);
    unsigned* bar   = (unsigned*)(ws + OFF_BAR);
    float*    out   = (float*)d_out;

    k_init<<<256, 256, 0, stream>>>(hidden, hta, bar);
    k_fold<<<dim3(48, 16), 256, 0, stream>>>(W_ih, W_in, wcomb);
    k_bcomb<<<768, 256, 0, stream>>>(W_ih, b_in, b_ih, bcomb);
    k_fused<<<256, 512, 0, stream>>>(W_hh, b_hh, wi, wcomb, bcomb, xg,
                                     hidden, hta, htb, hfin, bar);
    k_out<<<64, 256, 0, stream>>>(hfin, W_out, b_out, out);
    k_hout<<<256, 256, 0, stream>>>(hfin, out + 65536);
}